// Round 16
// baseline (833.474 us; speedup 1.0000x reference)
//
#include <hip/hip_runtime.h>

#define N_NODES 100000
#define N_EDGES 3200000
#define D 64
#define G_GRAPHS 64
#define L_LAYERS 5
#define BN_EPS 1e-5f
#define RPW 8
#define NBUCK 196     // dst>>9 buckets (512 nodes each; 196*512 >= 100000)
#define BSHIFT 9
#define BMASK 511
#define NPB 512       // partition blocks
#define EPB 6250      // edges per partition block (512*6250 = E)
#define TOTC (NBUCK * NPB)   // 100352 flattened (bucket, block) counts
#define SCAN_CH 392   // 256 blocks x 392 >= TOTC

typedef __fp16 h2 __attribute__((ext_vector_type(2)));
union h2u { unsigned u; h2 h; };
typedef __fp16 v8h __attribute__((ext_vector_type(8)));  // 8 f16 (MFMA A/B frag)
typedef float v4f __attribute__((ext_vector_type(4)));   // MFMA C/D frag

__device__ __forceinline__ unsigned pkf16(float a, float b) {  // RTZ pack
    h2u x; x.h = __builtin_amdgcn_cvt_pkrtz(a, b); return x.u;
}
__device__ __forceinline__ float dot2(unsigned a, unsigned b, float c) {
    h2u x, y; x.u = a; y.u = b;
    return __builtin_amdgcn_fdot2(x.h, y.h, c, false);
}
__device__ __forceinline__ unsigned pk_add(unsigned a, unsigned b) {
    h2u x, y, o; x.u = a; y.u = b; o.h = x.h + y.h; return o.u;
}
__device__ __forceinline__ unsigned pk_fma(unsigned a, unsigned b, unsigned c) {
    h2u x, y, z, o; x.u = a; y.u = b; z.u = c;
    o.h = x.h * y.h + z.h; return o.u;
}
__device__ __forceinline__ unsigned pk_relu(unsigned a) {
    h2u x, z, o; x.u = a; z.u = 0;
#if __has_builtin(__builtin_elementwise_max)
    o.h = __builtin_elementwise_max(x.h, z.h);
#else
    o.h[0] = x.h[0] > (__fp16)0.f ? x.h[0] : (__fp16)0.f;
    o.h[1] = x.h[1] > (__fp16)0.f ? x.h[1] : (__fp16)0.f;
#endif
    return o.u;
}
__device__ __forceinline__ ushort f2h(float f) {  // RNE f32->f16
    union { __fp16 h; ushort s; } u; u.h = (__fp16)f; return u.s;
}
__device__ __forceinline__ float h2f_lo(unsigned v) { h2u u; u.u = v; return (float)u.h[0]; }
__device__ __forceinline__ float h2f_hi(unsigned v) { h2u u; u.u = v; return (float)u.h[1]; }

// async global->LDS, 16B per lane; LDS dest is wave-uniform base + lane*16
__device__ __forceinline__ void gload_lds16(const void* g, void* l) {
    __builtin_amdgcn_global_load_lds(
        (const __attribute__((address_space(1))) unsigned int*)g,
        (__attribute__((address_space(3))) unsigned int*)l, 16, 0, 0);
}

__device__ __forceinline__ unsigned quant15(float a) {
    float q = fminf(fmaxf((a + 8.0f) * 2048.0f, 0.0f), 32767.0f);
    return (unsigned)__float2int_rn(q);
}

// ---------------- x -> f16 ---------------------------------------------------
__global__ __launch_bounds__(256) void xcvt_kernel(const float* __restrict__ x,
                                                   ushort* __restrict__ xh) {
    const float4* x4 = (const float4*)x;
    ushort4* o4 = (ushort4*)xh;
    const int total = N_NODES * D / 4;
    for (int i = blockIdx.x * blockDim.x + threadIdx.x; i < total;
         i += gridDim.x * blockDim.x) {
        float4 v = x4[i];
        ushort4 o;
        o.x = f2h(v.x); o.y = f2h(v.y); o.z = f2h(v.z); o.w = f2h(v.w);
        o4[i] = o;
    }
}

// ---------------- pass A: per-block bucket histogram -------------------------
__global__ __launch_bounds__(256) void hist512_kernel(const int* __restrict__ ei,
                                                      int* __restrict__ gcount) {
    __shared__ int cnt[NBUCK];
    const int tid = threadIdx.x, b = blockIdx.x;
    if (tid < NBUCK) cnt[tid] = 0;
    __syncthreads();
    const int ebase = b * EPB, eend = ebase + EPB;
    for (int r = 0; r < 25; ++r) {
        int e = ebase + r * 256 + tid;
        if (e < eend) atomicAdd(&cnt[ei[N_EDGES + e] >> BSHIFT], 1);
    }
    __syncthreads();
    if (tid < NBUCK) gcount[tid * NPB + b] = cnt[tid];   // bucket-major
}

// ---------------- pass B: parallel exclusive scan of 196*512 counts ----------
__global__ __launch_bounds__(256) void scan_partial(const int* __restrict__ gcount,
                                                    int* __restrict__ bsum) {
    __shared__ int sc[256];
    int b = blockIdx.x, t = threadIdx.x;
    int s = b * SCAN_CH, e = min(s + SCAN_CH, TOTC);
    int sum = 0;
    for (int idx = s + t; idx < e; idx += 256) sum += gcount[idx];
    sc[t] = sum;
    __syncthreads();
    for (int o = 128; o; o >>= 1) {
        if (t < o) sc[t] += sc[t + o];
        __syncthreads();
    }
    if (!t) bsum[b] = sc[0];
}

__global__ __launch_bounds__(256) void scan_base(const int* __restrict__ bsum,
                                                 int* __restrict__ bbase,
                                                 int* __restrict__ bucketbase) {
    __shared__ int sc[256];
    int t = threadIdx.x;
    int v = bsum[t];
    sc[t] = v;
    __syncthreads();
    for (int o = 1; o < 256; o <<= 1) {
        int x = (t >= o) ? sc[t - o] : 0;
        __syncthreads();
        sc[t] += x;
        __syncthreads();
    }
    bbase[t] = sc[t] - v;
    if (t == 0) bucketbase[NBUCK] = N_EDGES;
}

__global__ __launch_bounds__(256) void scan_apply(const int* __restrict__ gcount,
                                                  const int* __restrict__ bbase,
                                                  int* __restrict__ ofs,
                                                  int* __restrict__ bucketbase) {
    __shared__ int sc[256];
    int b = blockIdx.x, t = threadIdx.x;
    int s = b * SCAN_CH, e = min(s + SCAN_CH, TOTC);
    int base = bbase[b];
    for (int t0 = s; t0 < e; t0 += 256) {
        int idx = t0 + t;
        int v = (idx < e) ? gcount[idx] : 0;
        sc[t] = v;
        __syncthreads();
        for (int o = 1; o < 256; o <<= 1) {
            int x = (t >= o) ? sc[t - o] : 0;
            __syncthreads();
            sc[t] += x;
            __syncthreads();
        }
        if (idx < e) {
            int ex = base + sc[t] - v;
            ofs[idx] = ex;
            if ((idx & (NPB - 1)) == 0) bucketbase[idx / NPB] = ex;
        }
        base += sc[255];
        __syncthreads();
    }
}

// ---------------- pass C: ordered partition write (stream-contiguous) --------
// entry: x = src, y = (dst & 511) | (attr15 << 9)
__global__ __launch_bounds__(256) void part_kernel(const int* __restrict__ ei,
                                                   const float* __restrict__ ea,
                                                   const int* __restrict__ ofs,
                                                   uint2* __restrict__ inter) {
    __shared__ int cur[NBUCK];
    const int tid = threadIdx.x, b = blockIdx.x;
    if (tid < NBUCK) cur[tid] = ofs[tid * NPB + b];
    __syncthreads();
    const int ebase = b * EPB, eend = ebase + EPB;
    for (int r = 0; r < 25; ++r) {
        int e = ebase + r * 256 + tid;
        if (e < eend) {
            int s = ei[e];
            int d = ei[N_EDGES + e];
            float a = ea[e];
            int k = d >> BSHIFT;
            int p = atomicAdd(&cur[k], 1);
            uint2 v;
            v.x = (unsigned)s;
            v.y = (unsigned)(d & BMASK) | (quant15(a) << BSHIFT);
            inter[p] = v;
        }
    }
}

// ---------------- pass D: per-bucket exact sort (196 blocks, L2-local) -------
__global__ __launch_bounds__(256) void bucket_kernel(const uint2* __restrict__ inter,
                                                     const int* __restrict__ bucketbase,
                                                     unsigned* __restrict__ perm,
                                                     int* __restrict__ row_ptr) {
    __shared__ int hist[512];
    __shared__ int part[256];
    const int b = blockIdx.x, t = threadIdx.x;
    const int beg = bucketbase[b], end = bucketbase[b + 1];
    const int cnt = end - beg;
    const uint2* reg = inter + beg;
    const int n0 = b << BSHIFT;
    const int nn = min(512, N_NODES - n0);
    hist[t] = 0; hist[t + 256] = 0;
    __syncthreads();
    for (int i = t; i < cnt; i += 256)
        atomicAdd(&hist[reg[i].y & BMASK], 1);
    __syncthreads();
    int h0 = hist[2 * t], h1 = hist[2 * t + 1];
    int s = h0 + h1;
    part[t] = s;
    __syncthreads();
    for (int o = 1; o < 256; o <<= 1) {
        int v = (t >= o) ? part[t - o] : 0;
        __syncthreads();
        part[t] += v;
        __syncthreads();
    }
    int ex = beg + part[t] - s;
    if (2 * t < nn)     row_ptr[n0 + 2 * t] = ex;
    if (2 * t + 1 < nn) row_ptr[n0 + 2 * t + 1] = ex + h0;
    hist[2 * t] = ex;
    hist[2 * t + 1] = ex + h0;
    __syncthreads();
    for (int i = t; i < cnt; i += 256) {
        uint2 v = reg[i];
        int p = atomicAdd(&hist[v.y & BMASK], 1);
        perm[p] = (v.x << 15) | (v.y >> BSHIFT);
    }
    if (b == NBUCK - 1 && t == 0) row_ptr[N_NODES] = N_EDGES;
}

// ---------------- fused GINE layer (f16 h, packed gather, MFMA GEMMs) --------
__global__ __launch_bounds__(256, 3) void layer_kernel(
    const ushort* __restrict__ hbf,      // [N][D] f16
    const int* __restrict__ row_ptr,
    const unsigned* __restrict__ perm,
    const float* __restrict__ eps, int layer,
    const float* __restrict__ edgeW, const float* __restrict__ edgeB,
    const float* __restrict__ W1, const float* __restrict__ b1,
    const float* __restrict__ bng, const float* __restrict__ bnb,
    const float* __restrict__ W2, const float* __restrict__ b2,
    const int* __restrict__ batch,
    ushort* __restrict__ hout,           // [N][D] f16
    float* __restrict__ pooled /* [G][D] this layer */) {
    __shared__ ushort Wf1[4096];                        // 8 KB frag-linear f16 (bn-folded)
    __shared__ ushort Wf2[4096];                        // 8 KB frag-linear f16
    __shared__ __align__(16) ushort stage[4][3][1024];  // 24 KB: 3-slot ring/wave
    __shared__ __align__(16) ushort zbufs[4][512];      // 4 KB: z rows 0-7/wave (swizzled)
    __shared__ __align__(16) unsigned pbuf[4][544];     // 8.5 KB: perm segment + pad

    const float inv_std = rsqrtf(1.0f + BN_EPS);
    const int tid = threadIdx.x;
    // B-fragments: frag = nt*2+kh; elem (l,j) = W[kh*32+(l>>4)*8+j][nt*16+(l&15)]
    for (int idx = tid; idx < 4096; idx += 256) {
        int frag = idx >> 9;
        int l = (idx >> 3) & 63;
        int j = idx & 7;
        int kh = frag & 1, nt = frag >> 1;
        int k = kh * 32 + ((l >> 4) << 3) + j;
        int c = nt * 16 + (l & 15);
        Wf1[idx] = f2h(W1[k * 64 + c] * (bng[c] * inv_std));
        Wf2[idx] = f2h(W2[k * 64 + c]);
    }
    __syncthreads();

    const int lane = tid & 63;
    const int q = lane & 15;
    const int grp = lane >> 4;
    const int wid = tid >> 6;
    const int wv = blockIdx.x * 4 + wid;
    const int r0 = wv * RPW;          // N = 12500*8 exactly
    if (r0 >= N_NODES) return;

    int rpv = 0;
    if (lane < 9) rpv = row_ptr[r0 + lane];
    int cval = __shfl(rpv, lane + 1) - rpv;    // degree, valid lane<8
    int bval = 0;
    if (lane < RPW) bval = batch[r0 + lane];
    const int segbase = __shfl(rpv, 0);
    const int seglen  = __shfl(rpv, 8) - segbase;

    const float ev = 1.0f + eps[layer];
    const float QDEC = 4.8828125e-4f;  // 1/2048
    float w4[4], b4[4];
    unsigned wcc[4], bcc[4];           // (w[c],w[c]) / (b[c],b[c]) f16 pairs
    {
        float4 t = ((const float4*)edgeW)[q];
        w4[0] = t.x; w4[1] = t.y; w4[2] = t.z; w4[3] = t.w;
        float4 u = ((const float4*)edgeB)[q];
        b4[0] = u.x; b4[1] = u.y; b4[2] = u.z; b4[3] = u.w;
        #pragma unroll
        for (int c = 0; c < 4; ++c) {
            wcc[c] = pkf16(w4[c], w4[c]);
            bcc[c] = pkf16(b4[c], b4[c]);
        }
    }
    // per-lane epilogue biases indexed by output col = nt*16 + (lane&15)
    float blv1n[4], blv2n[4];
    #pragma unroll
    for (int nt = 0; nt < 4; ++nt) {
        int c = nt * 16 + (lane & 15);
        blv1n[nt] = fmaf(b1[c], bng[c] * inv_std, bnb[c]);
        blv2n[nt] = b2[c];
    }
    const uint2* h8 = (const uint2*)hbf;   // 4 f16 per uint2... (indexed by *16 per row)

    // z-row sink: pack f16, store swizzled into zbufs (grp0 lanes only)
    auto store_z = [&](int ai, float z0, float z1, float z2, float z3) {
        if (grp == 0) {
            unsigned lo = pkf16(z0, z1);
            unsigned hi = pkf16(z2, z3);
            int ad = (ai * 128 + q * 8) ^ ((ai & 7) << 4);
            *(uint2*)((char*)&zbufs[wid][0] + ad) = make_uint2(lo, hi);
        }
    };

    if (seglen <= 512) {
        // ---- fast path: perm segment in LDS, depth-2 async gather ----
        if (seglen > 0) {
            gload_lds16(perm + segbase + lane * 4, &pbuf[wid][0]);
            if (seglen > 256)
                gload_lds16(perm + segbase + 256 + lane * 4, &pbuf[wid][256]);
        }
        asm volatile("s_waitcnt vmcnt(0)" ::: "memory");  // pbuf ready
        // zero the pad (sanitizes masked lanes: src 0, finite row)
        for (int i = seglen + lane; i < 544; i += 64) pbuf[wid][i] = 0;

        auto nchunks = [&](int i) { return (__shfl(cval, i) + 15) >> 4; };
        int nTot = 0;
        #pragma unroll
        for (int i = 0; i < RPW; ++i) nTot += nchunks(i);

        int i_iss = 0, c_iss = 0;
        while (i_iss < RPW && nchunks(i_iss) == 0) ++i_iss;
        auto issue1 = [&](int slot) {
            int rb = __shfl(rpv, i_iss) - segbase;
            int so = rb + (c_iss << 4);
            ushort* sb = &stage[wid][slot][0];
            int eloc = lane >> 3, sub = lane & 7;
            #pragma unroll
            for (int j = 0; j < 2; ++j) {
                unsigned pe = pbuf[wid][so + (j << 3) + eloc];
                gload_lds16(hbf + (size_t)(pe >> 15) * D + sub * 8, sb + j * 512);
            }
            ++c_iss;
            while (i_iss < RPW) {
                if (c_iss < nchunks(i_iss)) break;
                ++i_iss; c_iss = 0;
            }
        };
        // edge-pair packed accumulate: lane handles edges e0,e0+1 x comps 4q..4q+3
        auto accumulate = [&](const ushort* sb, int rb, int ebase, int cr, float* agg) {
            #pragma unroll
            for (int k = 0; k < 2; ++k) {
                int e0 = (k << 3) | (grp << 1);
                int base = rb + ebase + e0;
                unsigned pe0 = pbuf[wid][base];
                unsigned pe1 = pbuf[wid][base + 1];
                int rem = cr - (ebase + e0);
                unsigned mpk = (rem >= 2) ? 0x3C003C00u
                             : ((rem == 1) ? 0x00003C00u : 0u);
                float a0 = fmaf((float)(pe0 & 0x7FFFu), QDEC, -8.0f);
                float a1 = fmaf((float)(pe1 & 0x7FFFu), QDEC, -8.0f);
                unsigned apk = pkf16(a0, a1);
                uint2 hv0 = *(const uint2*)(sb + (e0 << 6) + (q << 2));
                uint2 hv1 = *(const uint2*)(sb + ((e0 + 1) << 6) + (q << 2));
                unsigned p0 = __builtin_amdgcn_perm(hv1.x, hv0.x, 0x05040100u);
                unsigned p1 = __builtin_amdgcn_perm(hv1.x, hv0.x, 0x07060302u);
                unsigned p2 = __builtin_amdgcn_perm(hv1.y, hv0.y, 0x05040100u);
                unsigned p3 = __builtin_amdgcn_perm(hv1.y, hv0.y, 0x07060302u);
                unsigned m0 = pk_relu(pk_add(p0, pk_fma(apk, wcc[0], bcc[0])));
                unsigned m1 = pk_relu(pk_add(p1, pk_fma(apk, wcc[1], bcc[1])));
                unsigned m2 = pk_relu(pk_add(p2, pk_fma(apk, wcc[2], bcc[2])));
                unsigned m3 = pk_relu(pk_add(p3, pk_fma(apk, wcc[3], bcc[3])));
                agg[0] = dot2(m0, mpk, agg[0]);
                agg[1] = dot2(m1, mpk, agg[1]);
                agg[2] = dot2(m2, mpk, agg[2]);
                agg[3] = dot2(m3, mpk, agg[3]);
            }
        };

        int nIss = 0, sIss = 0, nCon = 0, sCon = 0;
        if (nIss < nTot) { issue1(sIss); sIss = 1; ++nIss; }
        if (nIss < nTot) { issue1(sIss); sIss = 2; ++nIss; }

        for (int ai = 0; ai < RPW; ++ai) {
            int cr = __shfl(cval, ai);
            int nch = (cr + 15) >> 4;
            int rb = __shfl(rpv, ai) - segbase;
            uint2 hs = h8[(size_t)(r0 + ai) * 16 + q];   // self row (4 f16)
            float agg[4] = {0.f, 0.f, 0.f, 0.f};
            for (int ac = 0; ac < nch; ++ac) {
                if (nIss < nTot) {
                    issue1(sIss);
                    sIss = (sIss == 2) ? 0 : sIss + 1;
                    ++nIss;
                    asm volatile("s_waitcnt vmcnt(4)" ::: "memory");
                } else if (nIss - nCon == 2) {
                    asm volatile("s_waitcnt vmcnt(2)" ::: "memory");
                } else {
                    asm volatile("s_waitcnt vmcnt(0)" ::: "memory");
                }
                accumulate(&stage[wid][sCon][0], rb, ac << 4, cr, agg);
                sCon = (sCon == 2) ? 0 : sCon + 1;
                ++nCon;
            }
            #pragma unroll
            for (int c = 0; c < 4; ++c) {
                agg[c] += __shfl_xor(agg[c], 16);
                agg[c] += __shfl_xor(agg[c], 32);
            }
            store_z(ai,
                    fmaf(ev, h2f_lo(hs.x), agg[0]), fmaf(ev, h2f_hi(hs.x), agg[1]),
                    fmaf(ev, h2f_lo(hs.y), agg[2]), fmaf(ev, h2f_hi(hs.y), agg[3]));
        }
    } else {
        // ---- rare fallback: serial direct gather (no staging) ----
        for (int ai = 0; ai < RPW; ++ai) {
            int cr = __shfl(cval, ai);
            int rbg = __shfl(rpv, ai);
            uint2 hs = h8[(size_t)(r0 + ai) * 16 + q];
            float agg[4] = {0.f, 0.f, 0.f, 0.f};
            for (int k = grp; k < cr; k += 4) {
                unsigned pe = perm[rbg + k];
                float a = fmaf((float)(pe & 0x7FFFu), QDEC, -8.0f);
                uint2 hv = h8[(size_t)(pe >> 15) * 16 + q];
                agg[0] += fmaxf(fmaf(a, w4[0], b4[0]) + h2f_lo(hv.x), 0.f);
                agg[1] += fmaxf(fmaf(a, w4[1], b4[1]) + h2f_hi(hv.x), 0.f);
                agg[2] += fmaxf(fmaf(a, w4[2], b4[2]) + h2f_lo(hv.y), 0.f);
                agg[3] += fmaxf(fmaf(a, w4[3], b4[3]) + h2f_hi(hv.y), 0.f);
            }
            #pragma unroll
            for (int c = 0; c < 4; ++c) {
                agg[c] += __shfl_xor(agg[c], 16);
                agg[c] += __shfl_xor(agg[c], 32);
            }
            store_z(ai,
                    fmaf(ev, h2f_lo(hs.x), agg[0]), fmaf(ev, h2f_hi(hs.x), agg[1]),
                    fmaf(ev, h2f_lo(hs.y), agg[2]), fmaf(ev, h2f_hi(hs.y), agg[3]));
        }
    }

    // ---- MFMA GEMM phase (per wave; gathers drained, slot 0 reusable) -------
    const int arow = lane & 15, agrp = lane >> 4;
    ushort* yb = &stage[wid][0][0];           // y1 bounce buffer (slot 0)
    v8h a1[2];
    #pragma unroll
    for (int kh = 0; kh < 2; ++kh) {
        int ad = (arow * 128 + kh * 64 + agrp * 16) ^ ((arow & 7) << 4);
        a1[kh] = *(const v8h*)((char*)&zbufs[wid][0] + ad);
    }
    #pragma unroll
    for (int nt = 0; nt < 4; ++nt) {
        v4f acc = {0.f, 0.f, 0.f, 0.f};
        acc = __builtin_amdgcn_mfma_f32_16x16x32_f16(
            a1[0], *(const v8h*)&Wf1[(nt * 2 + 0) * 512 + lane * 8], acc, 0, 0, 0);
        acc = __builtin_amdgcn_mfma_f32_16x16x32_f16(
            a1[1], *(const v8h*)&Wf1[(nt * 2 + 1) * 512 + lane * 8], acc, 0, 0, 0);
        #pragma unroll
        for (int i = 0; i < 4; ++i) {
            float y = fmaxf(acc[i] + blv1n[nt], 0.f);
            int row = agrp * 4 + i;
            int ad = (row * 128 + (nt * 16 + arow) * 2) ^ ((row & 7) << 4);
            *(ushort*)((char*)yb + ad) = f2h(y);
        }
    }
    v8h a2[2];
    #pragma unroll
    for (int kh = 0; kh < 2; ++kh) {
        int ad = (arow * 128 + kh * 64 + agrp * 16) ^ ((arow & 7) << 4);
        a2[kh] = *(const v8h*)((char*)yb + ad);
    }
    float y2v[16];   // [nt*4+i], static-indexed
    #pragma unroll
    for (int nt = 0; nt < 4; ++nt) {
        v4f acc = {0.f, 0.f, 0.f, 0.f};
        acc = __builtin_amdgcn_mfma_f32_16x16x32_f16(
            a2[0], *(const v8h*)&Wf2[(nt * 2 + 0) * 512 + lane * 8], acc, 0, 0, 0);
        acc = __builtin_amdgcn_mfma_f32_16x16x32_f16(
            a2[1], *(const v8h*)&Wf2[(nt * 2 + 1) * 512 + lane * 8], acc, 0, 0, 0);
        #pragma unroll
        for (int i = 0; i < 4; ++i)
            y2v[nt * 4 + i] = fmaxf(acc[i] + blv2n[nt], 0.f);
    }
    // output rows 0-7 (lanes agrp<2 hold real rows); rows 8-15 are pad garbage
    if (agrp < 2) {
        #pragma unroll
        for (int i = 0; i < 4; ++i) {
            int row = agrp * 4 + i;
            #pragma unroll
            for (int nt = 0; nt < 4; ++nt)
                hout[(size_t)(r0 + row) * D + nt * 16 + arow] =
                    f2h(y2v[nt * 4 + i]);
        }
    }
    // pooling: fast path when all 8 rows share one graph (sorted batch)
    int g0 = __shfl(bval, 0), g7 = __shfl(bval, 7);
    if (g0 == g7) {
        #pragma unroll
        for (int nt = 0; nt < 4; ++nt) {
            float m = fmaxf(fmaxf(y2v[nt * 4 + 0], y2v[nt * 4 + 1]),
                            fmaxf(y2v[nt * 4 + 2], y2v[nt * 4 + 3]));
            m = fmaxf(m, __shfl_xor(m, 16));   // combine rows 0-3 with 4-7
            if (lane < 16)
                atomicMax((unsigned*)&pooled[g0 * D + nt * 16 + lane],
                          __float_as_uint(m));
        }
    } else {
        if (agrp < 2) {
            #pragma unroll
            for (int i = 0; i < 4; ++i) {
                int g = __shfl(bval, agrp * 4 + i);
                #pragma unroll
                for (int nt = 0; nt < 4; ++nt)
                    atomicMax((unsigned*)&pooled[g * D + nt * 16 + arow],
                              __float_as_uint(y2v[nt * 4 + i]));
            }
        }
    }
}

// ---------------- MLP head ---------------------------------------------------
__global__ __launch_bounds__(256) void mlp_kernel(
    const float* __restrict__ pooled,  // [5][G][D]
    const float* __restrict__ l1W, const float* __restrict__ l1b,
    const float* __restrict__ l2W, const float* __restrict__ l2b,
    float* __restrict__ out) {
    __shared__ float gl[5 * D];
    __shared__ float tl[4 * D];
    int gid = blockIdx.x;
    int tid = threadIdx.x;
    for (int idx = tid; idx < 5 * D; idx += 256) {
        int k = idx >> 6;
        int d = idx & 63;
        gl[idx] = pooled[k * (G_GRAPHS * D) + gid * D + d];
    }
    __syncthreads();
    {
        float acc = l1b[tid];
        for (int m = 0; m < 5 * D; ++m)
            acc = fmaf(gl[m], l1W[m * 256 + tid], acc);
        tl[tid] = fmaxf(acc, 0.0f);
    }
    __syncthreads();
    if (tid < 5) {
        float acc = l2b[tid];
        for (int m = 0; m < 4 * D; ++m)
            acc = fmaf(tl[m], l2W[m * 5 + tid], acc);
        out[gid * 5 + tid] = acc;
    }
}

extern "C" void kernel_launch(void* const* d_in, const int* in_sizes, int n_in,
                              void* d_out, int out_size, void* d_ws, size_t ws_size,
                              hipStream_t stream) {
    const float* x     = (const float*)d_in[0];
    const int*   ei    = (const int*)d_in[1];
    const float* ea    = (const float*)d_in[2];
    const int*   batch = (const int*)d_in[3];
    const float* eps   = (const float*)d_in[4];
    const float* edgeW = (const float*)d_in[5];
    const float* edgeB = (const float*)d_in[6];
    const float* W1    = (const float*)d_in[7];
    const float* b1    = (const float*)d_in[8];
    const float* bng   = (const float*)d_in[9];
    const float* bnb   = (const float*)d_in[10];
    const float* W2    = (const float*)d_in[11];
    const float* b2    = (const float*)d_in[12];
    const float* l1W   = (const float*)d_in[13];
    const float* l1b   = (const float*)d_in[14];
    const float* l2W   = (const float*)d_in[15];
    const float* l2b   = (const float*)d_in[16];
    float* out = (float*)d_out;

    char* ws = (char*)d_ws;
    size_t nbf = (size_t)N_NODES * D * sizeof(ushort);  // 12.8 MB
    size_t off = 0;
    ushort* hbfA  = (ushort*)(ws + off); off += nbf;
    ushort* hbfB  = (ushort*)(ws + off); off += nbf;
    float* pooled = (float*)(ws + off);  off += (size_t)L_LAYERS * G_GRAPHS * D * sizeof(float);
    off = (off + 15) & ~(size_t)15;
    unsigned* perm = (unsigned*)(ws + off); off += (size_t)N_EDGES * sizeof(unsigned); // 12.8 MB
    int* row_ptr  = (int*)(ws + off);    off += (size_t)(N_NODES + 1) * sizeof(int);
    int* gcount   = (int*)(ws + off);    off += (size_t)TOTC * sizeof(int);   // 401 KB
    int* ofs      = (int*)(ws + off);    off += (size_t)TOTC * sizeof(int);   // 401 KB
    int* bucketbase = (int*)(ws + off);  off += (NBUCK + 4) * sizeof(int);
    int* bsum     = (int*)(ws + off);    off += 256 * sizeof(int);
    int* bbase    = (int*)(ws + off);    off += 256 * sizeof(int);
    off = (off + 15) & ~(size_t)15;
    uint2* inter  = (uint2*)(ws + off);  off += (size_t)N_EDGES * sizeof(uint2);  // 25.6 MB

    hipMemsetAsync(pooled, 0, (size_t)L_LAYERS * G_GRAPHS * D * sizeof(float), stream);

    xcvt_kernel<<<1024, 256, 0, stream>>>(x, hbfA);
    hist512_kernel<<<NPB, 256, 0, stream>>>(ei, gcount);
    scan_partial<<<256, 256, 0, stream>>>(gcount, bsum);
    scan_base<<<1, 256, 0, stream>>>(bsum, bbase, bucketbase);
    scan_apply<<<256, 256, 0, stream>>>(gcount, bbase, ofs, bucketbase);
    part_kernel<<<NPB, 256, 0, stream>>>(ei, ea, ofs, inter);
    bucket_kernel<<<NBUCK, 256, 0, stream>>>(inter, bucketbase, perm, row_ptr);

    const int waves  = (N_NODES + RPW - 1) / RPW;   // 12500
    const int blocks = (waves + 3) / 4;             // 3125

    const ushort* hcur = hbfA;
    for (int i = 0; i < L_LAYERS; ++i) {
        ushort* hnext = (i & 1) ? hbfA : hbfB;
        layer_kernel<<<blocks, 256, 0, stream>>>(
            hcur, row_ptr, perm, eps, i,
            edgeW + i * D, edgeB + i * D,
            W1 + i * D * D, b1 + i * D,
            bng + i * D, bnb + i * D,
            W2 + i * D * D, b2 + i * D,
            batch, hnext, pooled + i * G_GRAPHS * D);
        hcur = hnext;
    }
    mlp_kernel<<<G_GRAPHS, 256, 0, stream>>>(pooled, l1W, l1b, l2W, l2b, out);
}

// Round 17
// 746.825 us; speedup vs baseline: 1.1160x; 1.1160x over previous
//
#include <hip/hip_runtime.h>

#define N_NODES 100000
#define N_EDGES 3200000
#define D 64
#define G_GRAPHS 64
#define L_LAYERS 5
#define BN_EPS 1e-5f
#define RPW 8
#define NBUCK 196     // dst>>9 buckets (512 nodes each; 196*512 >= 100000)
#define BSHIFT 9
#define BMASK 511
#define NPB 512       // partition blocks
#define EPB 6250      // edges per partition block (512*6250 = E)
#define TOTC (NBUCK * NPB)   // 100352 flattened (bucket, block) counts
#define SCAN_CH 392   // 256 blocks x 392 >= TOTC

typedef __fp16 h2 __attribute__((ext_vector_type(2)));
union h2u { unsigned u; h2 h; };
typedef short v8s __attribute__((ext_vector_type(8)));   // 8 bf16 (MFMA A/B frag)
typedef float v4f __attribute__((ext_vector_type(4)));   // MFMA C/D frag

__device__ __forceinline__ unsigned pkf16(float a, float b) {
    h2u x; x.h = __builtin_amdgcn_cvt_pkrtz(a, b); return x.u;
}

__device__ __forceinline__ unsigned short f2bf(float f) {  // RNE f32->bf16
    unsigned int u = __float_as_uint(f);
    u += 0x7FFFu + ((u >> 16) & 1u);
    return (unsigned short)(u >> 16);
}
__device__ __forceinline__ float bf2f(unsigned short v) {
    return __uint_as_float((unsigned int)v << 16);
}

// async global->LDS, 16B per lane; LDS dest is wave-uniform base + lane*16
__device__ __forceinline__ void gload_lds16(const void* g, void* l) {
    __builtin_amdgcn_global_load_lds(
        (const __attribute__((address_space(1))) unsigned int*)g,
        (__attribute__((address_space(3))) unsigned int*)l, 16, 0, 0);
}

__device__ __forceinline__ unsigned quant15(float a) {
    float q = fminf(fmaxf((a + 8.0f) * 2048.0f, 0.0f), 32767.0f);
    return (unsigned)__float2int_rn(q);
}

// ---------------- x -> bf16 -------------------------------------------------
__global__ __launch_bounds__(256) void xcvt_kernel(const float* __restrict__ x,
                                                   ushort* __restrict__ xbf) {
    const float4* x4 = (const float4*)x;
    ushort4* o4 = (ushort4*)xbf;
    const int total = N_NODES * D / 4;
    for (int i = blockIdx.x * blockDim.x + threadIdx.x; i < total;
         i += gridDim.x * blockDim.x) {
        float4 v = x4[i];
        ushort4 o;
        o.x = f2bf(v.x); o.y = f2bf(v.y); o.z = f2bf(v.z); o.w = f2bf(v.w);
        o4[i] = o;
    }
}

// ---------------- pass A: per-block bucket histogram -------------------------
__global__ __launch_bounds__(256) void hist512_kernel(const int* __restrict__ ei,
                                                      int* __restrict__ gcount) {
    __shared__ int cnt[NBUCK];
    const int tid = threadIdx.x, b = blockIdx.x;
    if (tid < NBUCK) cnt[tid] = 0;
    __syncthreads();
    const int ebase = b * EPB, eend = ebase + EPB;
    for (int r = 0; r < 25; ++r) {
        int e = ebase + r * 256 + tid;
        if (e < eend) atomicAdd(&cnt[ei[N_EDGES + e] >> BSHIFT], 1);
    }
    __syncthreads();
    if (tid < NBUCK) gcount[tid * NPB + b] = cnt[tid];   // bucket-major
}

// ---------------- pass B: parallel exclusive scan of 196*512 counts ----------
__global__ __launch_bounds__(256) void scan_partial(const int* __restrict__ gcount,
                                                    int* __restrict__ bsum) {
    __shared__ int sc[256];
    int b = blockIdx.x, t = threadIdx.x;
    int s = b * SCAN_CH, e = min(s + SCAN_CH, TOTC);
    int sum = 0;
    for (int idx = s + t; idx < e; idx += 256) sum += gcount[idx];
    sc[t] = sum;
    __syncthreads();
    for (int o = 128; o; o >>= 1) {
        if (t < o) sc[t] += sc[t + o];
        __syncthreads();
    }
    if (!t) bsum[b] = sc[0];
}

__global__ __launch_bounds__(256) void scan_base(const int* __restrict__ bsum,
                                                 int* __restrict__ bbase,
                                                 int* __restrict__ bucketbase) {
    __shared__ int sc[256];
    int t = threadIdx.x;
    int v = bsum[t];
    sc[t] = v;
    __syncthreads();
    for (int o = 1; o < 256; o <<= 1) {
        int x = (t >= o) ? sc[t - o] : 0;
        __syncthreads();
        sc[t] += x;
        __syncthreads();
    }
    bbase[t] = sc[t] - v;
    if (t == 0) bucketbase[NBUCK] = N_EDGES;
}

__global__ __launch_bounds__(256) void scan_apply(const int* __restrict__ gcount,
                                                  const int* __restrict__ bbase,
                                                  int* __restrict__ ofs,
                                                  int* __restrict__ bucketbase) {
    __shared__ int sc[256];
    int b = blockIdx.x, t = threadIdx.x;
    int s = b * SCAN_CH, e = min(s + SCAN_CH, TOTC);
    int base = bbase[b];
    for (int t0 = s; t0 < e; t0 += 256) {
        int idx = t0 + t;
        int v = (idx < e) ? gcount[idx] : 0;
        sc[t] = v;
        __syncthreads();
        for (int o = 1; o < 256; o <<= 1) {
            int x = (t >= o) ? sc[t - o] : 0;
            __syncthreads();
            sc[t] += x;
            __syncthreads();
        }
        if (idx < e) {
            int ex = base + sc[t] - v;
            ofs[idx] = ex;
            if ((idx & (NPB - 1)) == 0) bucketbase[idx / NPB] = ex;
        }
        base += sc[255];
        __syncthreads();
    }
}

// ---------------- pass C: ordered partition write (stream-contiguous) --------
// entry: x = src, y = (dst & 511) | (attr15 << 9)
__global__ __launch_bounds__(256) void part_kernel(const int* __restrict__ ei,
                                                   const float* __restrict__ ea,
                                                   const int* __restrict__ ofs,
                                                   uint2* __restrict__ inter) {
    __shared__ int cur[NBUCK];
    const int tid = threadIdx.x, b = blockIdx.x;
    if (tid < NBUCK) cur[tid] = ofs[tid * NPB + b];
    __syncthreads();
    const int ebase = b * EPB, eend = ebase + EPB;
    for (int r = 0; r < 25; ++r) {
        int e = ebase + r * 256 + tid;
        if (e < eend) {
            int s = ei[e];
            int d = ei[N_EDGES + e];
            float a = ea[e];
            int k = d >> BSHIFT;
            int p = atomicAdd(&cur[k], 1);
            uint2 v;
            v.x = (unsigned)s;
            v.y = (unsigned)(d & BMASK) | (quant15(a) << BSHIFT);
            inter[p] = v;
        }
    }
}

// ---------------- pass D: per-bucket exact sort (196 blocks, L2-local) -------
__global__ __launch_bounds__(256) void bucket_kernel(const uint2* __restrict__ inter,
                                                     const int* __restrict__ bucketbase,
                                                     unsigned* __restrict__ perm,
                                                     int* __restrict__ row_ptr) {
    __shared__ int hist[512];
    __shared__ int part[256];
    const int b = blockIdx.x, t = threadIdx.x;
    const int beg = bucketbase[b], end = bucketbase[b + 1];
    const int cnt = end - beg;
    const uint2* reg = inter + beg;
    const int n0 = b << BSHIFT;
    const int nn = min(512, N_NODES - n0);
    hist[t] = 0; hist[t + 256] = 0;
    __syncthreads();
    for (int i = t; i < cnt; i += 256)
        atomicAdd(&hist[reg[i].y & BMASK], 1);
    __syncthreads();
    int h0 = hist[2 * t], h1 = hist[2 * t + 1];
    int s = h0 + h1;
    part[t] = s;
    __syncthreads();
    for (int o = 1; o < 256; o <<= 1) {
        int v = (t >= o) ? part[t - o] : 0;
        __syncthreads();
        part[t] += v;
        __syncthreads();
    }
    int ex = beg + part[t] - s;
    if (2 * t < nn)     row_ptr[n0 + 2 * t] = ex;
    if (2 * t + 1 < nn) row_ptr[n0 + 2 * t + 1] = ex + h0;
    hist[2 * t] = ex;
    hist[2 * t + 1] = ex + h0;
    __syncthreads();
    for (int i = t; i < cnt; i += 256) {
        uint2 v = reg[i];
        int p = atomicAdd(&hist[v.y & BMASK], 1);
        perm[p] = (v.x << 15) | (v.y >> BSHIFT);
    }
    if (b == NBUCK - 1 && t == 0) row_ptr[N_NODES] = N_EDGES;
}

// ---------------- fused GINE layer (R15: gather pipeline + MFMA GEMMs) -------
__global__ __launch_bounds__(256, 3) void layer_kernel(
    const ushort* __restrict__ hbf,      // [N][D] bf16
    const int* __restrict__ row_ptr,
    const unsigned* __restrict__ perm,
    const float* __restrict__ eps, int layer,
    const float* __restrict__ edgeW, const float* __restrict__ edgeB,
    const float* __restrict__ W1, const float* __restrict__ b1,
    const float* __restrict__ bng, const float* __restrict__ bnb,
    const float* __restrict__ W2, const float* __restrict__ b2,
    const int* __restrict__ batch,
    ushort* __restrict__ hout,           // [N][D] bf16
    float* __restrict__ pooled /* [G][D] this layer */) {
    __shared__ ushort Wf1[4096];                        // 8 KB frag-linear bf16 (bn-folded)
    __shared__ ushort Wf2[4096];                        // 8 KB frag-linear bf16
    __shared__ __align__(16) ushort stage[4][3][1024];  // 24 KB: 3-slot ring/wave
    __shared__ __align__(16) ushort zbufs[4][512];      // 4 KB: z rows 0-7/wave (swizzled)
    __shared__ __align__(16) unsigned pbuf[4][512];     // 8 KB: perm segment/wave
    // (zbufs A-frag reads for pad rows 8-15 overrun into pbuf: garbage, discarded;
    //  OOB src indices (17 bits) stay inside the two 12.8MB h buffers -> finite bf16)

    const float inv_std = rsqrtf(1.0f + BN_EPS);
    const int tid = threadIdx.x;
    // Build B-fragments: frag = nt*2+kh; elem (l,j) = W[kh*32+(l>>4)*8+j][nt*16+(l&15)]
    for (int idx = tid; idx < 4096; idx += 256) {
        int frag = idx >> 9;
        int l = (idx >> 3) & 63;
        int j = idx & 7;
        int kh = frag & 1, nt = frag >> 1;
        int k = kh * 32 + ((l >> 4) << 3) + j;
        int c = nt * 16 + (l & 15);
        Wf1[idx] = f2bf(W1[k * 64 + c] * (bng[c] * inv_std));
        Wf2[idx] = f2bf(W2[k * 64 + c]);
    }
    __syncthreads();

    const int lane = tid & 63;
    const int q = lane & 15;
    const int grp = lane >> 4;
    const int wid = tid >> 6;
    const int wv = blockIdx.x * 4 + wid;
    const int r0 = wv * RPW;          // N = 12500*8 exactly
    if (r0 >= N_NODES) return;

    int rpv = 0;
    if (lane < 9) rpv = row_ptr[r0 + lane];
    int cval = __shfl(rpv, lane + 1) - rpv;    // degree, valid lane<8
    int bval = 0;
    if (lane < RPW) bval = batch[r0 + lane];
    const int segbase = __shfl(rpv, 0);
    const int seglen  = __shfl(rpv, 8) - segbase;

    const float ev = 1.0f + eps[layer];
    const float QDEC = 4.8828125e-4f;  // 1/2048
    float w4[4], b4[4];
    {
        float4 t = ((const float4*)edgeW)[q];
        w4[0] = t.x; w4[1] = t.y; w4[2] = t.z; w4[3] = t.w;
        float4 u = ((const float4*)edgeB)[q];
        b4[0] = u.x; b4[1] = u.y; b4[2] = u.z; b4[3] = u.w;
    }
    // per-lane epilogue biases indexed by output col = nt*16 + (lane&15)
    float blv1n[4], blv2n[4];
    #pragma unroll
    for (int nt = 0; nt < 4; ++nt) {
        int c = nt * 16 + (lane & 15);
        blv1n[nt] = fmaf(b1[c], bng[c] * inv_std, bnb[c]);
        blv2n[nt] = b2[c];
    }
    const ushort4* h4 = (const ushort4*)hbf;

    // z-row sink: pack bf16, store swizzled into zbufs (grp0 lanes only)
    auto store_z = [&](int ai, float z0, float z1, float z2, float z3) {
        if (grp == 0) {
            unsigned lo = (unsigned)f2bf(z0) | ((unsigned)f2bf(z1) << 16);
            unsigned hi = (unsigned)f2bf(z2) | ((unsigned)f2bf(z3) << 16);
            int ad = (ai * 128 + q * 8) ^ ((ai & 7) << 4);
            *(uint2*)((char*)&zbufs[wid][0] + ad) = make_uint2(lo, hi);
        }
    };

    if (seglen <= 512) {
        // ---- fast path: perm segment in LDS, depth-2 async gather ----
        if (seglen > 0) {
            gload_lds16(perm + segbase + lane * 4, &pbuf[wid][0]);
            if (seglen > 256)
                gload_lds16(perm + segbase + 256 + lane * 4, &pbuf[wid][256]);
        }
        asm volatile("s_waitcnt vmcnt(0)" ::: "memory");  // pbuf ready

        auto nchunks = [&](int i) { return (__shfl(cval, i) + 15) >> 4; };
        int nTot = 0;
        #pragma unroll
        for (int i = 0; i < RPW; ++i) nTot += nchunks(i);

        int i_iss = 0, c_iss = 0;
        while (i_iss < RPW && nchunks(i_iss) == 0) ++i_iss;
        auto issue1 = [&](int slot) {
            int rb = __shfl(rpv, i_iss) - segbase;
            int so = rb + (c_iss << 4);
            ushort* sb = &stage[wid][slot][0];
            int eloc = lane >> 3, sub = lane & 7;
            #pragma unroll
            for (int j = 0; j < 2; ++j) {
                int idx = min(so + (j << 3) + eloc, 511);
                unsigned pe = pbuf[wid][idx];
                gload_lds16(hbf + (size_t)(pe >> 15) * D + sub * 8, sb + j * 512);
            }
            ++c_iss;
            while (i_iss < RPW) {
                if (c_iss < nchunks(i_iss)) break;
                ++i_iss; c_iss = 0;
            }
        };
        auto accumulate = [&](const ushort* sb, int rb, int ebase, int cr, float* agg) {
            #pragma unroll
            for (int k = 0; k < 4; ++k) {
                int eidx = (k << 2) | grp;
                int idx = min(rb + ebase + eidx, 511);
                unsigned pe = pbuf[wid][idx];
                float m = (ebase + eidx < cr) ? 1.0f : 0.0f;
                float a = fmaf((float)(pe & 0x7FFFu), QDEC, -8.0f);
                ushort4 hv = *(const ushort4*)(sb + (eidx << 6) + (q << 2));
                agg[0] = fmaf(m, fmaxf(fmaf(a, w4[0], b4[0]) + bf2f(hv.x), 0.f), agg[0]);
                agg[1] = fmaf(m, fmaxf(fmaf(a, w4[1], b4[1]) + bf2f(hv.y), 0.f), agg[1]);
                agg[2] = fmaf(m, fmaxf(fmaf(a, w4[2], b4[2]) + bf2f(hv.z), 0.f), agg[2]);
                agg[3] = fmaf(m, fmaxf(fmaf(a, w4[3], b4[3]) + bf2f(hv.w), 0.f), agg[3]);
            }
        };

        int nIss = 0, sIss = 0, nCon = 0, sCon = 0;
        if (nIss < nTot) { issue1(sIss); sIss = 1; ++nIss; }
        if (nIss < nTot) { issue1(sIss); sIss = 2; ++nIss; }

        for (int ai = 0; ai < RPW; ++ai) {
            int cr = __shfl(cval, ai);
            int nch = (cr + 15) >> 4;
            int rb = __shfl(rpv, ai) - segbase;
            ushort4 hs4 = h4[(size_t)(r0 + ai) * 16 + q];   // self row
            float agg[4] = {0.f, 0.f, 0.f, 0.f};
            for (int ac = 0; ac < nch; ++ac) {
                if (nIss < nTot) {
                    issue1(sIss);
                    sIss = (sIss == 2) ? 0 : sIss + 1;
                    ++nIss;
                    asm volatile("s_waitcnt vmcnt(4)" ::: "memory");
                } else if (nIss - nCon == 2) {
                    asm volatile("s_waitcnt vmcnt(2)" ::: "memory");
                } else {
                    asm volatile("s_waitcnt vmcnt(0)" ::: "memory");
                }
                accumulate(&stage[wid][sCon][0], rb, ac << 4, cr, agg);
                sCon = (sCon == 2) ? 0 : sCon + 1;
                ++nCon;
            }
            #pragma unroll
            for (int c = 0; c < 4; ++c) {
                agg[c] += __shfl_xor(agg[c], 16);
                agg[c] += __shfl_xor(agg[c], 32);
            }
            store_z(ai,
                    fmaf(ev, bf2f(hs4.x), agg[0]), fmaf(ev, bf2f(hs4.y), agg[1]),
                    fmaf(ev, bf2f(hs4.z), agg[2]), fmaf(ev, bf2f(hs4.w), agg[3]));
        }
    } else {
        // ---- rare fallback: serial direct gather (no staging) ----
        for (int ai = 0; ai < RPW; ++ai) {
            int cr = __shfl(cval, ai);
            int rbg = __shfl(rpv, ai);
            ushort4 hs4 = h4[(size_t)(r0 + ai) * 16 + q];
            float agg[4] = {0.f, 0.f, 0.f, 0.f};
            for (int k = grp; k < cr; k += 4) {
                unsigned pe = perm[rbg + k];
                float a = fmaf((float)(pe & 0x7FFFu), QDEC, -8.0f);
                ushort4 hv = h4[(size_t)(pe >> 15) * 16 + q];
                agg[0] += fmaxf(fmaf(a, w4[0], b4[0]) + bf2f(hv.x), 0.f);
                agg[1] += fmaxf(fmaf(a, w4[1], b4[1]) + bf2f(hv.y), 0.f);
                agg[2] += fmaxf(fmaf(a, w4[2], b4[2]) + bf2f(hv.z), 0.f);
                agg[3] += fmaxf(fmaf(a, w4[3], b4[3]) + bf2f(hv.w), 0.f);
            }
            #pragma unroll
            for (int c = 0; c < 4; ++c) {
                agg[c] += __shfl_xor(agg[c], 16);
                agg[c] += __shfl_xor(agg[c], 32);
            }
            store_z(ai,
                    fmaf(ev, bf2f(hs4.x), agg[0]), fmaf(ev, bf2f(hs4.y), agg[1]),
                    fmaf(ev, bf2f(hs4.z), agg[2]), fmaf(ev, bf2f(hs4.w), agg[3]));
        }
    }

    // ---- MFMA GEMM phase (per wave; all gathers drained, slots idle) --------
    // A layout: lane holds A[row=lane&15][k=kh*32+(lane>>4)*8+j]
    // C layout: lane holds C[row=(lane>>4)*4+i][col=nt*16+(lane&15)]
    const int arow = lane & 15, agrp = lane >> 4;
    ushort* yb = &stage[wid][0][0];           // y1 bounce buffer (slot 0)
    v8s a1[2];
    #pragma unroll
    for (int kh = 0; kh < 2; ++kh) {
        int ad = (arow * 128 + kh * 64 + agrp * 16) ^ ((arow & 7) << 4);
        a1[kh] = *(const v8s*)((char*)&zbufs[wid][0] + ad);
    }
    #pragma unroll
    for (int nt = 0; nt < 4; ++nt) {
        v4f acc = {0.f, 0.f, 0.f, 0.f};
        acc = __builtin_amdgcn_mfma_f32_16x16x32_bf16(
            a1[0], *(const v8s*)&Wf1[(nt * 2 + 0) * 512 + lane * 8], acc, 0, 0, 0);
        acc = __builtin_amdgcn_mfma_f32_16x16x32_bf16(
            a1[1], *(const v8s*)&Wf1[(nt * 2 + 1) * 512 + lane * 8], acc, 0, 0, 0);
        #pragma unroll
        for (int i = 0; i < 4; ++i) {
            float y = fmaxf(acc[i] + blv1n[nt], 0.f);
            int row = agrp * 4 + i;
            int ad = (row * 128 + (nt * 16 + arow) * 2) ^ ((row & 7) << 4);
            *(ushort*)((char*)yb + ad) = f2bf(y);
        }
    }
    v8s a2[2];
    #pragma unroll
    for (int kh = 0; kh < 2; ++kh) {
        int ad = (arow * 128 + kh * 64 + agrp * 16) ^ ((arow & 7) << 4);
        a2[kh] = *(const v8s*)((char*)yb + ad);
    }
    float y2v[16];   // [nt*4+i], static-indexed
    #pragma unroll
    for (int nt = 0; nt < 4; ++nt) {
        v4f acc = {0.f, 0.f, 0.f, 0.f};
        acc = __builtin_amdgcn_mfma_f32_16x16x32_bf16(
            a2[0], *(const v8s*)&Wf2[(nt * 2 + 0) * 512 + lane * 8], acc, 0, 0, 0);
        acc = __builtin_amdgcn_mfma_f32_16x16x32_bf16(
            a2[1], *(const v8s*)&Wf2[(nt * 2 + 1) * 512 + lane * 8], acc, 0, 0, 0);
        #pragma unroll
        for (int i = 0; i < 4; ++i)
            y2v[nt * 4 + i] = fmaxf(acc[i] + blv2n[nt], 0.f);
    }
    // output rows 0-7 (lanes agrp<2 hold real rows); rows 8-15 are pad garbage
    if (agrp < 2) {
        #pragma unroll
        for (int i = 0; i < 4; ++i) {
            int row = agrp * 4 + i;
            #pragma unroll
            for (int nt = 0; nt < 4; ++nt)
                hout[(size_t)(r0 + row) * D + nt * 16 + arow] =
                    (ushort)f2bf(y2v[nt * 4 + i]);
        }
    }
    // pooling: fast path when all 8 rows share one graph (sorted batch)
    int g0 = __shfl(bval, 0), g7 = __shfl(bval, 7);
    if (g0 == g7) {
        #pragma unroll
        for (int nt = 0; nt < 4; ++nt) {
            float m = fmaxf(fmaxf(y2v[nt * 4 + 0], y2v[nt * 4 + 1]),
                            fmaxf(y2v[nt * 4 + 2], y2v[nt * 4 + 3]));
            m = fmaxf(m, __shfl_xor(m, 16));   // combine rows 0-3 with 4-7
            if (lane < 16)
                atomicMax((unsigned*)&pooled[g0 * D + nt * 16 + lane],
                          __float_as_uint(m));
        }
    } else {
        if (agrp < 2) {
            #pragma unroll
            for (int i = 0; i < 4; ++i) {
                int g = __shfl(bval, agrp * 4 + i);
                #pragma unroll
                for (int nt = 0; nt < 4; ++nt)
                    atomicMax((unsigned*)&pooled[g * D + nt * 16 + arow],
                              __float_as_uint(y2v[nt * 4 + i]));
            }
        }
    }
}

// ---------------- MLP head ---------------------------------------------------
__global__ __launch_bounds__(256) void mlp_kernel(
    const float* __restrict__ pooled,  // [5][G][D]
    const float* __restrict__ l1W, const float* __restrict__ l1b,
    const float* __restrict__ l2W, const float* __restrict__ l2b,
    float* __restrict__ out) {
    __shared__ float gl[5 * D];
    __shared__ float tl[4 * D];
    int gid = blockIdx.x;
    int tid = threadIdx.x;
    for (int idx = tid; idx < 5 * D; idx += 256) {
        int k = idx >> 6;
        int d = idx & 63;
        gl[idx] = pooled[k * (G_GRAPHS * D) + gid * D + d];
    }
    __syncthreads();
    {
        float acc = l1b[tid];
        for (int m = 0; m < 5 * D; ++m)
            acc = fmaf(gl[m], l1W[m * 256 + tid], acc);
        tl[tid] = fmaxf(acc, 0.0f);
    }
    __syncthreads();
    if (tid < 5) {
        float acc = l2b[tid];
        for (int m = 0; m < 4 * D; ++m)
            acc = fmaf(tl[m], l2W[m * 5 + tid], acc);
        out[gid * 5 + tid] = acc;
    }
}

extern "C" void kernel_launch(void* const* d_in, const int* in_sizes, int n_in,
                              void* d_out, int out_size, void* d_ws, size_t ws_size,
                              hipStream_t stream) {
    const float* x     = (const float*)d_in[0];
    const int*   ei    = (const int*)d_in[1];
    const float* ea    = (const float*)d_in[2];
    const int*   batch = (const int*)d_in[3];
    const float* eps   = (const float*)d_in[4];
    const float* edgeW = (const float*)d_in[5];
    const float* edgeB = (const float*)d_in[6];
    const float* W1    = (const float*)d_in[7];
    const float* b1    = (const float*)d_in[8];
    const float* bng   = (const float*)d_in[9];
    const float* bnb   = (const float*)d_in[10];
    const float* W2    = (const float*)d_in[11];
    const float* b2    = (const float*)d_in[12];
    const float* l1W   = (const float*)d_in[13];
    const float* l1b   = (const float*)d_in[14];
    const float* l2W   = (const float*)d_in[15];
    const float* l2b   = (const float*)d_in[16];
    float* out = (float*)d_out;

    char* ws = (char*)d_ws;
    size_t nbf = (size_t)N_NODES * D * sizeof(ushort);  // 12.8 MB
    size_t off = 0;
    ushort* hbfA  = (ushort*)(ws + off); off += nbf;
    ushort* hbfB  = (ushort*)(ws + off); off += nbf;
    float* pooled = (float*)(ws + off);  off += (size_t)L_LAYERS * G_GRAPHS * D * sizeof(float);
    off = (off + 15) & ~(size_t)15;
    unsigned* perm = (unsigned*)(ws + off); off += (size_t)N_EDGES * sizeof(unsigned); // 12.8 MB
    int* row_ptr  = (int*)(ws + off);    off += (size_t)(N_NODES + 1) * sizeof(int);
    int* gcount   = (int*)(ws + off);    off += (size_t)TOTC * sizeof(int);   // 401 KB
    int* ofs      = (int*)(ws + off);    off += (size_t)TOTC * sizeof(int);   // 401 KB
    int* bucketbase = (int*)(ws + off);  off += (NBUCK + 4) * sizeof(int);
    int* bsum     = (int*)(ws + off);    off += 256 * sizeof(int);
    int* bbase    = (int*)(ws + off);    off += 256 * sizeof(int);
    off = (off + 15) & ~(size_t)15;
    uint2* inter  = (uint2*)(ws + off);  off += (size_t)N_EDGES * sizeof(uint2);  // 25.6 MB

    hipMemsetAsync(pooled, 0, (size_t)L_LAYERS * G_GRAPHS * D * sizeof(float), stream);

    xcvt_kernel<<<1024, 256, 0, stream>>>(x, hbfA);
    hist512_kernel<<<NPB, 256, 0, stream>>>(ei, gcount);
    scan_partial<<<256, 256, 0, stream>>>(gcount, bsum);
    scan_base<<<1, 256, 0, stream>>>(bsum, bbase, bucketbase);
    scan_apply<<<256, 256, 0, stream>>>(gcount, bbase, ofs, bucketbase);
    part_kernel<<<NPB, 256, 0, stream>>>(ei, ea, ofs, inter);
    bucket_kernel<<<NBUCK, 256, 0, stream>>>(inter, bucketbase, perm, row_ptr);

    const int waves  = (N_NODES + RPW - 1) / RPW;   // 12500
    const int blocks = (waves + 3) / 4;             // 3125

    const ushort* hcur = hbfA;
    for (int i = 0; i < L_LAYERS; ++i) {
        ushort* hnext = (i & 1) ? hbfA : hbfB;
        layer_kernel<<<blocks, 256, 0, stream>>>(
            hcur, row_ptr, perm, eps, i,
            edgeW + i * D, edgeB + i * D,
            W1 + i * D * D, b1 + i * D,
            bng + i * D, bnb + i * D,
            W2 + i * D * D, b2 + i * D,
            batch, hnext, pooled + i * G_GRAPHS * D);
        hcur = hnext;
    }
    mlp_kernel<<<G_GRAPHS, 256, 0, stream>>>(pooled, l1W, l1b, l2W, l2b, out);
}